// Round 2
// baseline (811.018 us; speedup 1.0000x reference)
//
#include <hip/hip_runtime.h>
#include <stdint.h>

// Problem constants
#define B_  4
#define T_  2048
#define D_  1024
#define H_  16
#define ND_ 64
#define M_  (B_ * T_)   // 8192 rows

typedef unsigned short u16;
typedef __bf16 bf8  __attribute__((ext_vector_type(8)));
typedef float  f4   __attribute__((ext_vector_type(4)));
typedef u16    u16x8 __attribute__((ext_vector_type(8)));

__device__ inline float bf2f(u16 b) {
    unsigned int x = ((unsigned int)b) << 16;
    return __builtin_bit_cast(float, x);
}
__device__ inline u16 f2bf(float f) {  // RNE, finite inputs only
    unsigned int x = __builtin_bit_cast(unsigned int, f);
    x += 0x7fffu + ((x >> 16) & 1u);
    return (u16)(x >> 16);
}
__device__ inline f4 mfma16(bf8 a, bf8 b, f4 c) {
    return __builtin_amdgcn_mfma_f32_16x16x32_bf16(a, b, c, 0, 0, 0);
}
// async global->LDS, 16B per lane; LDS dest = wave-uniform base + lane*16
__device__ inline void async16(const void* g, void* l) {
    auto gp = reinterpret_cast<const __attribute__((address_space(1))) unsigned int*>(
        reinterpret_cast<uintptr_t>(g));
    auto lp = reinterpret_cast<__attribute__((address_space(3))) unsigned int*>(
        reinterpret_cast<uintptr_t>(l));
    __builtin_amdgcn_global_load_lds(gp, lp, 16, 0, 0);
}

// ---------------------------------------------------------------------------
// fp32 -> bf16 elementwise convert (n divisible by 8)
// ---------------------------------------------------------------------------
__global__ __launch_bounds__(256)
void cvt_bf16(const float* __restrict__ in, u16* __restrict__ out, int n) {
    int i = (blockIdx.x * blockDim.x + threadIdx.x) * 8;
    if (i + 8 <= n) {
        float4 a = *(const float4*)(in + i);
        float4 b = *(const float4*)(in + i + 4);
        u16x8 o;
        o[0] = f2bf(a.x); o[1] = f2bf(a.y); o[2] = f2bf(a.z); o[3] = f2bf(a.w);
        o[4] = f2bf(b.x); o[5] = f2bf(b.y); o[6] = f2bf(b.z); o[7] = f2bf(b.w);
        *(u16x8*)(out + i) = o;
    }
}

// ---------------------------------------------------------------------------
// C[M,N] = A[M,K] @ W[N,K]^T + bias   (A,W bf16, fp32 accum, bias fp32)
// MODE 0: write C row-major [M,N] as FP32 (final output)
// MODE 1: write bf16 head layout: out[((b*H + h)*T + t)*64 + d], m=b*T+t, n=h*64+d
// Fixed: M=8192, N=1024, K=1024. Grid (8, 64), block 256.
// ---------------------------------------------------------------------------
template <int MODE>
__global__ __launch_bounds__(256, 2)
void gemm_bt(const u16* __restrict__ A, const u16* __restrict__ W,
             const float* __restrict__ bias, void* __restrict__ CoutV) {
    constexpr int K = 1024;
    constexpr int N = 1024;
    __shared__ __attribute__((aligned(16))) u16 sA[128 * 32];
    __shared__ __attribute__((aligned(16))) u16 sB[128 * 32];
    const int tid  = threadIdx.x;
    const int wave = tid >> 6;
    const int lane = tid & 63;
    const int m0 = blockIdx.y * 128;
    const int n0 = blockIdx.x * 128;
    const int wm = (wave & 1) * 64;
    const int wn = (wave >> 1) * 64;

    f4 acc[4][4] = {};

    // staging: each wave fills rows [wave*32, wave*32+32) of both tiles
    const int srow = wave * 32 + (lane >> 2);
    const int scol = (lane & 3) * 8;
    const u16* gA = A + (size_t)(m0 + srow) * K + scol;
    const u16* gB = W + (size_t)(n0 + srow) * K + scol;
    u16* lA0 = sA + (wave * 32) * 32;
    u16* lA1 = sA + (wave * 32 + 16) * 32;
    u16* lB0 = sB + (wave * 32) * 32;
    u16* lB1 = sB + (wave * 32 + 16) * 32;

    const int row = lane & 15;
    const int qo  = (lane >> 4) * 8;

    for (int k0 = 0; k0 < K; k0 += 32) {
        async16(gA + k0, lA0);
        async16(gA + k0 + (size_t)16 * K, lA1);
        async16(gB + k0, lB0);
        async16(gB + k0 + (size_t)16 * K, lB1);
        __syncthreads();

        bf8 af[4], bfr[4];
#pragma unroll
        for (int i = 0; i < 4; i++)
            af[i] = *(const bf8*)(sA + (wm + i * 16 + row) * 32 + qo);
#pragma unroll
        for (int i = 0; i < 4; i++)
            bfr[i] = *(const bf8*)(sB + (wn + i * 16 + row) * 32 + qo);
#pragma unroll
        for (int mi = 0; mi < 4; mi++)
#pragma unroll
            for (int ni = 0; ni < 4; ni++)
                acc[mi][ni] = mfma16(af[mi], bfr[ni], acc[mi][ni]);
        __syncthreads();
    }

    // epilogue: C row m = m0+wm+mi*16+(lane>>4)*4+r, col n = n0+wn+ni*16+(lane&15)
#pragma unroll
    for (int ni = 0; ni < 4; ni++) {
        const int n = n0 + wn + ni * 16 + row;
        const float bv = bias[n];
#pragma unroll
        for (int mi = 0; mi < 4; mi++) {
#pragma unroll
            for (int r = 0; r < 4; r++) {
                const int m = m0 + wm + mi * 16 + (lane >> 4) * 4 + r;
                const float v = acc[mi][ni][r] + bv;
                if (MODE == 1) {
                    // b=m>>11, t=m&2047, h=n>>6, d=n&63
                    size_t idx = (((size_t)((m >> 11) * H_ + (n >> 6)) * T_) + (m & (T_ - 1))) * ND_ +
                                 (n & (ND_ - 1));
                    ((u16*)CoutV)[idx] = f2bf(v);
                } else {
                    ((float*)CoutV)[(size_t)m * N + n] = v;
                }
            }
        }
    }
}

// ---------------------------------------------------------------------------
// Column softmax stats: for each (b,h,k): m_k = max_{q>=k} s[q,k],
// invL_k = 1/sum_{q>=k} exp(s-m_k), s = (Q[q].K[k])/8.
// Grid (T/64, B*H), block 256; wave w owns 16 columns.
// ---------------------------------------------------------------------------
__global__ __launch_bounds__(256)
void col_stats(const u16* __restrict__ Qh, const u16* __restrict__ Kh,
               float* __restrict__ Mc, float* __restrict__ Ic) {
    const int bh   = blockIdx.y;
    const int wave = threadIdx.x >> 6;
    const int lane = threadIdx.x & 63;
    const int k0   = blockIdx.x * 64 + wave * 16;
    const int kcol = k0 + (lane & 15);
    const int qo   = (lane >> 4) * 8;
    const u16* Qb = Qh + (size_t)bh * T_ * ND_;
    const u16* Kb = Kh + (size_t)bh * T_ * ND_;

    const bf8 b0 = *(const bf8*)(Kb + (size_t)kcol * ND_ + qo);
    const bf8 b1 = *(const bf8*)(Kb + (size_t)kcol * ND_ + 32 + qo);

    float mx = -1e30f, l = 0.f;
    for (int qt = k0; qt < T_; qt += 16) {
        const u16* qrow = Qb + (size_t)(qt + (lane & 15)) * ND_;
        bf8 a0 = *(const bf8*)(qrow + qo);
        bf8 a1 = *(const bf8*)(qrow + 32 + qo);
        f4 s = {0.f, 0.f, 0.f, 0.f};
        s = mfma16(a0, b0, s);
        s = mfma16(a1, b1, s);
#pragma unroll
        for (int r = 0; r < 4; r++) {
            const int q = qt + (lane >> 4) * 4 + r;
            if (q >= kcol) {
                const float sv = s[r] * 0.125f;
                const float nm = fmaxf(mx, sv);
                l  = l * __expf(mx - nm) + __expf(sv - nm);
                mx = nm;
            }
        }
    }
    // combine the 4 quads (lanes l, l^16, l^32, l^48) — -1e30 sentinel avoids NaN
#pragma unroll
    for (int off = 16; off < 64; off <<= 1) {
        const float om = __shfl_xor(mx, off);
        const float ol = __shfl_xor(l, off);
        const float nm = fmaxf(mx, om);
        l  = l * __expf(mx - nm) + ol * __expf(om - nm);
        mx = nm;
    }
    if (lane < 16) {
        Mc[(size_t)bh * T_ + kcol] = mx;
        Ic[(size_t)bh * T_ + kcol] = 1.f / l;
    }
}

// ---------------------------------------------------------------------------
// O[q,:] = sum_{k<=q} exp(s[q,k]-m_k)*invL_k * V[k,:]   per (b,h)
// Grid (T/64, B*H), block 256; wave w owns q rows [qb+16w, qb+16w+16).
// Writes AO in [B,T,D] bf16 layout for the final projection.
// ---------------------------------------------------------------------------
__global__ __launch_bounds__(256)
void attn_out(const u16* __restrict__ Qh, const u16* __restrict__ Kh,
              const u16* __restrict__ Vh, const float* __restrict__ Mc,
              const float* __restrict__ Ic, u16* __restrict__ AO) {
    __shared__ __attribute__((aligned(16))) u16 sK[32 * 64];   // [k][d]
    __shared__ __attribute__((aligned(16))) u16 sVt[64 * 32];  // [d][k]
    __shared__ __attribute__((aligned(16))) u16 sP[4][16 * 32];// per-wave [q][k]
    const int bh   = blockIdx.y;
    const int b    = bh >> 4;
    const int h    = bh & 15;
    const int qb   = blockIdx.x * 64;
    const int tid  = threadIdx.x;
    const int wave = tid >> 6;
    const int lane = tid & 63;
    const int qo   = (lane >> 4) * 8;
    const u16* Qb = Qh + (size_t)bh * T_ * ND_;
    const u16* Kb = Kh + (size_t)bh * T_ * ND_;
    const u16* Vb = Vh + (size_t)bh * T_ * ND_;
    const float* mc = Mc + (size_t)bh * T_;
    const float* ic = Ic + (size_t)bh * T_;

    const int qrow = qb + wave * 16 + (lane & 15);
    const bf8 aq0 = *(const bf8*)(Qb + (size_t)qrow * ND_ + qo);
    const bf8 aq1 = *(const bf8*)(Qb + (size_t)qrow * ND_ + 32 + qo);

    f4 o[4] = {};

    const int sr = tid >> 3;        // 0..31
    const int sc = (tid & 7) * 8;   // 0..56
    const int kend = qb + 64;

    for (int kt = 0; kt < kend; kt += 32) {
        // stage K tile [32][64] and V tile transposed [64][32]
        *(u16x8*)(sK + sr * 64 + sc) = *(const u16x8*)(Kb + (size_t)(kt + sr) * ND_ + sc);
        u16x8 vv = *(const u16x8*)(Vb + (size_t)(kt + sr) * ND_ + sc);
#pragma unroll
        for (int j = 0; j < 8; j++) sVt[(sc + j) * 32 + sr] = vv[j];
        __syncthreads();

        // scores + P (two 16-wide halves -> sP[wave] [16q][32k])
#pragma unroll
        for (int half = 0; half < 2; half++) {
            const int kl = half * 16 + (lane & 15);
            const int kg = kt + kl;
            bf8 kb0 = *(const bf8*)(sK + kl * 64 + qo);
            bf8 kb1 = *(const bf8*)(sK + kl * 64 + 32 + qo);
            f4 s = {0.f, 0.f, 0.f, 0.f};
            s = mfma16(aq0, kb0, s);
            s = mfma16(aq1, kb1, s);
            const float mk = mc[kg];
            const float il = ic[kg];
#pragma unroll
            for (int r = 0; r < 4; r++) {
                const int q = qb + wave * 16 + (lane >> 4) * 4 + r;
                const float p = (kg <= q) ? __expf(s[r] * 0.125f - mk) * il : 0.f;
                sP[wave][((lane >> 4) * 4 + r) * 32 + kl] = f2bf(p);
            }
        }
        __syncthreads();

        // PV: A = P[16q][32k] (A-layout), B = V[32k][64d] via sVt
        const bf8 ap = *(const bf8*)(&sP[wave][(lane & 15) * 32 + qo]);
#pragma unroll
        for (int nt = 0; nt < 4; nt++) {
            bf8 bv = *(const bf8*)(sVt + (nt * 16 + (lane & 15)) * 32 + qo);
            o[nt] = mfma16(ap, bv, o[nt]);
        }
        __syncthreads();
    }

    // write AO[B,T,D] bf16
#pragma unroll
    for (int nt = 0; nt < 4; nt++) {
#pragma unroll
        for (int r = 0; r < 4; r++) {
            const int q = qb + wave * 16 + (lane >> 4) * 4 + r;
            const int d = nt * 16 + (lane & 15);
            AO[((size_t)(b * T_ + q)) * D_ + h * ND_ + d] = f2bf(o[nt][r]);
        }
    }
}

// ---------------------------------------------------------------------------
extern "C" void kernel_launch(void* const* d_in, const int* in_sizes, int n_in,
                              void* d_out, int out_size, void* d_ws, size_t ws_size,
                              hipStream_t stream) {
    (void)in_sizes; (void)n_in; (void)out_size; (void)ws_size;
    // Inputs are FP32 per the reference (jnp.float32 everywhere).
    const float* q  = (const float*)d_in[0];
    // d_in[1]=k, d_in[2]=v are dead (reference bug: K,V projected from q)
    const float* wq = (const float*)d_in[3];
    const float* bq = (const float*)d_in[4];
    const float* wk = (const float*)d_in[5];
    const float* bk = (const float*)d_in[6];
    const float* wv = (const float*)d_in[7];
    const float* bv = (const float*)d_in[8];
    const float* wo = (const float*)d_in[9];
    const float* bo = (const float*)d_in[10];
    // d_in[11] = mask: structurally tril, handled via k<=q

    const size_t SZ = (size_t)M_ * D_;   // 8.39M elems per [B,T,D] tensor
    const size_t WSZ = (size_t)D_ * D_;  // 1.05M elems per weight
    u16* Qh  = (u16*)d_ws;               // [B,H,T,64] bf16
    u16* Kh  = Qh + SZ;
    u16* Vh  = Kh + SZ;
    u16* qbf = Vh + SZ;                  // q as bf16 [B,T,D]; reused as AO
    u16* AO  = qbf;
    u16* wqb = qbf + SZ;
    u16* wkb = wqb + WSZ;
    u16* wvb = wkb + WSZ;
    u16* wob = wvb + WSZ;
    float* Mc = (float*)(wob + WSZ);     // [B*H, T]
    float* Ic = Mc + (size_t)B_ * H_ * T_;

    // fp32 -> bf16 converts
    cvt_bf16<<<dim3(SZ / 8 / 256), 256, 0, stream>>>(q, qbf, (int)SZ);
    cvt_bf16<<<dim3(WSZ / 8 / 256), 256, 0, stream>>>(wq, wqb, (int)WSZ);
    cvt_bf16<<<dim3(WSZ / 8 / 256), 256, 0, stream>>>(wk, wkb, (int)WSZ);
    cvt_bf16<<<dim3(WSZ / 8 / 256), 256, 0, stream>>>(wv, wvb, (int)WSZ);
    cvt_bf16<<<dim3(WSZ / 8 / 256), 256, 0, stream>>>(wo, wob, (int)WSZ);

    dim3 gp(D_ / 128, M_ / 128);         // (8, 64)
    gemm_bt<1><<<gp, 256, 0, stream>>>(qbf, wqb, bq, Qh);
    gemm_bt<1><<<gp, 256, 0, stream>>>(qbf, wkb, bk, Kh);
    gemm_bt<1><<<gp, 256, 0, stream>>>(qbf, wvb, bv, Vh);

    dim3 ga(T_ / 64, B_ * H_);           // (32, 64)
    col_stats<<<ga, 256, 0, stream>>>(Qh, Kh, Mc, Ic);
    attn_out<<<ga, 256, 0, stream>>>(Qh, Kh, Vh, Mc, Ic, AO);

    gemm_bt<0><<<gp, 256, 0, stream>>>(AO, wob, bo, d_out);
}

// Round 4
// 604.046 us; speedup vs baseline: 1.3426x; 1.3426x over previous
//
#include <hip/hip_runtime.h>
#include <stdint.h>

// Problem constants
#define B_  4
#define T_  2048
#define D_  1024
#define H_  16
#define ND_ 64
#define M_  (B_ * T_)   // 8192 rows

typedef unsigned short u16;
typedef __bf16 bf8  __attribute__((ext_vector_type(8)));
typedef float  f4   __attribute__((ext_vector_type(4)));
typedef u16    u16x8 __attribute__((ext_vector_type(8)));

__device__ inline float bf2f(u16 b) {
    unsigned int x = ((unsigned int)b) << 16;
    return __builtin_bit_cast(float, x);
}
__device__ inline u16 f2bf(float f) {  // RNE, finite inputs only
    unsigned int x = __builtin_bit_cast(unsigned int, f);
    x += 0x7fffu + ((x >> 16) & 1u);
    return (u16)(x >> 16);
}
__device__ inline f4 mfma16(bf8 a, bf8 b, f4 c) {
    return __builtin_amdgcn_mfma_f32_16x16x32_bf16(a, b, c, 0, 0, 0);
}
// async global->LDS, 16B per lane; LDS dest = wave-uniform base + lane*16
__device__ inline void async16(const void* g, void* l) {
    auto gp = reinterpret_cast<const __attribute__((address_space(1))) unsigned int*>(
        reinterpret_cast<uintptr_t>(g));
    auto lp = reinterpret_cast<__attribute__((address_space(3))) unsigned int*>(
        reinterpret_cast<uintptr_t>(l));
    __builtin_amdgcn_global_load_lds(gp, lp, 16, 0, 0);
}

// ---------------------------------------------------------------------------
// fp32 -> bf16 elementwise convert (n divisible by 8)
// ---------------------------------------------------------------------------
__global__ __launch_bounds__(256)
void cvt_bf16(const float* __restrict__ in, u16* __restrict__ out, int n) {
    int i = (blockIdx.x * blockDim.x + threadIdx.x) * 8;
    if (i + 8 <= n) {
        float4 a = *(const float4*)(in + i);
        float4 b = *(const float4*)(in + i + 4);
        u16x8 o;
        o[0] = f2bf(a.x); o[1] = f2bf(a.y); o[2] = f2bf(a.z); o[3] = f2bf(a.w);
        o[4] = f2bf(b.x); o[5] = f2bf(b.y); o[6] = f2bf(b.z); o[7] = f2bf(b.w);
        *(u16x8*)(out + i) = o;
    }
}

// ---------------------------------------------------------------------------
// C[M,N] = A[M,K] @ W[N,K]^T + bias   (A,W bf16, fp32 accum, bias fp32)
// MODE 0: write C row-major [M,N] as FP32 (final output)
// MODE 1: write bf16 head layout: out[((b*H + h)*T + t)*64 + d]
// MODE 2: write bf16 transposed head layout: out[(bh*64 + d)*T + t]  (for V)
// Fixed: M=8192, N=1024, K=1024. Grid (8, 64), block 256.
// ---------------------------------------------------------------------------
template <int MODE>
__global__ __launch_bounds__(256, 2)
void gemm_bt(const u16* __restrict__ A, const u16* __restrict__ W,
             const float* __restrict__ bias, void* __restrict__ CoutV) {
    constexpr int K = 1024;
    constexpr int N = 1024;
    __shared__ __attribute__((aligned(16))) u16 sA[128 * 32];
    __shared__ __attribute__((aligned(16))) u16 sB[128 * 32];
    const int tid  = threadIdx.x;
    const int wave = tid >> 6;
    const int lane = tid & 63;
    const int m0 = blockIdx.y * 128;
    const int n0 = blockIdx.x * 128;
    const int wm = (wave & 1) * 64;
    const int wn = (wave >> 1) * 64;

    f4 acc[4][4] = {};

    const int srow = wave * 32 + (lane >> 2);
    const int scol = (lane & 3) * 8;
    const u16* gA = A + (size_t)(m0 + srow) * K + scol;
    const u16* gB = W + (size_t)(n0 + srow) * K + scol;
    u16* lA0 = sA + (wave * 32) * 32;
    u16* lA1 = sA + (wave * 32 + 16) * 32;
    u16* lB0 = sB + (wave * 32) * 32;
    u16* lB1 = sB + (wave * 32 + 16) * 32;

    const int row = lane & 15;
    const int qo  = (lane >> 4) * 8;

    for (int k0 = 0; k0 < K; k0 += 32) {
        async16(gA + k0, lA0);
        async16(gA + k0 + (size_t)16 * K, lA1);
        async16(gB + k0, lB0);
        async16(gB + k0 + (size_t)16 * K, lB1);
        __syncthreads();

        bf8 af[4], bfr[4];
#pragma unroll
        for (int i = 0; i < 4; i++)
            af[i] = *(const bf8*)(sA + (wm + i * 16 + row) * 32 + qo);
#pragma unroll
        for (int i = 0; i < 4; i++)
            bfr[i] = *(const bf8*)(sB + (wn + i * 16 + row) * 32 + qo);
#pragma unroll
        for (int mi = 0; mi < 4; mi++)
#pragma unroll
            for (int ni = 0; ni < 4; ni++)
                acc[mi][ni] = mfma16(af[mi], bfr[ni], acc[mi][ni]);
        __syncthreads();
    }

    // epilogue: C row m = m0+wm+mi*16+(lane>>4)*4+r, col n = n0+wn+ni*16+(lane&15)
#pragma unroll
    for (int ni = 0; ni < 4; ni++) {
        const int n = n0 + wn + ni * 16 + row;
        const float bv = bias[n];
#pragma unroll
        for (int mi = 0; mi < 4; mi++) {
#pragma unroll
            for (int r = 0; r < 4; r++) {
                const int m = m0 + wm + mi * 16 + (lane >> 4) * 4 + r;
                const float v = acc[mi][ni][r] + bv;
                if (MODE == 1) {
                    size_t idx = (((size_t)((m >> 11) * H_ + (n >> 6)) * T_) + (m & (T_ - 1))) * ND_ +
                                 (n & (ND_ - 1));
                    ((u16*)CoutV)[idx] = f2bf(v);
                } else if (MODE == 2) {
                    // Vt[(bh*64 + d)*T + t], bh=(m>>11)*16+(n>>6), d=n&63, t=m&2047
                    size_t idx = ((size_t)(((m >> 11) * H_ + (n >> 6)) * ND_ + (n & (ND_ - 1)))) * T_ +
                                 (m & (T_ - 1));
                    ((u16*)CoutV)[idx] = f2bf(v);
                } else {
                    ((float*)CoutV)[(size_t)m * N + n] = v;
                }
            }
        }
    }
}

// ---------------------------------------------------------------------------
// Column softmax stats: for each (b,h,k): m_k = max_{q>=k} s[q,k],
// invL_k = 1/sum_{q>=k} exp(s-m_k), s = (Q[q].K[k])/8.
// Grid (T/64, B*H), block 256; wave w owns 16 columns.
// ---------------------------------------------------------------------------
__global__ __launch_bounds__(256)
void col_stats(const u16* __restrict__ Qh, const u16* __restrict__ Kh,
               float* __restrict__ Mc, float* __restrict__ Ic) {
    const int bh   = blockIdx.y;
    const int wave = threadIdx.x >> 6;
    const int lane = threadIdx.x & 63;
    const int k0   = blockIdx.x * 64 + wave * 16;
    const int kcol = k0 + (lane & 15);
    const int qo   = (lane >> 4) * 8;
    const u16* Qb = Qh + (size_t)bh * T_ * ND_;
    const u16* Kb = Kh + (size_t)bh * T_ * ND_;

    const bf8 b0 = *(const bf8*)(Kb + (size_t)kcol * ND_ + qo);
    const bf8 b1 = *(const bf8*)(Kb + (size_t)kcol * ND_ + 32 + qo);

    float mx = -1e30f, l = 0.f;
    for (int qt = k0; qt < T_; qt += 16) {
        const u16* qrow = Qb + (size_t)(qt + (lane & 15)) * ND_;
        bf8 a0 = *(const bf8*)(qrow + qo);
        bf8 a1 = *(const bf8*)(qrow + 32 + qo);
        f4 s = {0.f, 0.f, 0.f, 0.f};
        s = mfma16(a0, b0, s);
        s = mfma16(a1, b1, s);
#pragma unroll
        for (int r = 0; r < 4; r++) {
            const int q = qt + (lane >> 4) * 4 + r;
            if (q >= kcol) {
                const float sv = s[r] * 0.125f;
                const float nm = fmaxf(mx, sv);
                l  = l * __expf(mx - nm) + __expf(sv - nm);
                mx = nm;
            }
        }
    }
#pragma unroll
    for (int off = 16; off < 64; off <<= 1) {
        const float om = __shfl_xor(mx, off);
        const float ol = __shfl_xor(l, off);
        const float nm = fmaxf(mx, om);
        l  = l * __expf(mx - nm) + ol * __expf(om - nm);
        mx = nm;
    }
    if (lane < 16) {
        Mc[(size_t)bh * T_ + kcol] = mx;
        Ic[(size_t)bh * T_ + kcol] = 1.f / l;
    }
}

// ---------------------------------------------------------------------------
// attn_out v2: 128 q rows/block, 64-key tiles, padded LDS (stride 72
// EVERYWHERE — round-3 bug was sP at stride 40 with 64-wide k tiles),
// register prefetch, per-wave sP (no middle barrier; DS pipe is in-order
// within a wave). Vt input pre-transposed per head: [bh][64 d][2048 t].
// Grid (B*H, T/128), heavy q-blocks dispatched first; block 256.
// ---------------------------------------------------------------------------
__global__ __launch_bounds__(256, 4)
void attn_out(const u16* __restrict__ Qh, const u16* __restrict__ Kh,
              const u16* __restrict__ Vt, const float* __restrict__ Mc,
              const float* __restrict__ Ic, u16* __restrict__ AO) {
    __shared__ __attribute__((aligned(16))) u16 sK[64 * 72];    // [k][d] pad 72
    __shared__ __attribute__((aligned(16))) u16 sVt[64 * 72];   // [d][k] pad 72
    __shared__ __attribute__((aligned(16))) u16 sP[4][32 * 72]; // per-wave [q][k<=64] pad 72
    const int bh   = blockIdx.x;
    const int b    = bh >> 4;
    const int h    = bh & 15;
    const int qb   = (int)(gridDim.y - 1 - blockIdx.y) * 128;  // heavy blocks dispatch first
    const int tid  = threadIdx.x;
    const int wave = tid >> 6;
    const int lane = tid & 63;
    const int l15  = lane & 15;
    const int quad = lane >> 4;
    const int qo   = quad * 8;

    const u16* Qb = Qh + (size_t)bh * T_ * ND_;
    const u16* Kb = Kh + (size_t)bh * T_ * ND_;
    const u16* Vb = Vt + (size_t)bh * ND_ * T_;   // [d][t]
    const float* mc = Mc + (size_t)bh * T_;
    const float* ic = Ic + (size_t)bh * T_;

    // wave owns q rows [qw, qw+32)
    const int qw = qb + wave * 32;
    bf8 aq[2][2];
#pragma unroll
    for (int qs = 0; qs < 2; qs++)
#pragma unroll
        for (int dh = 0; dh < 2; dh++)
            aq[qs][dh] = *(const bf8*)(Qb + (size_t)(qw + qs * 16 + l15) * ND_ + dh * 32 + qo);

    f4 o[2][4] = {};

    const int sr = tid >> 3;        // 0..31
    const int sc = (tid & 7) * 8;   // 0..56
    const int kend = qb + 128;

    // prefetch tile kt=0
    u16x8 pk0 = *(const u16x8*)(Kb + (size_t)sr * ND_ + sc);
    u16x8 pk1 = *(const u16x8*)(Kb + (size_t)(sr + 32) * ND_ + sc);
    u16x8 pv0 = *(const u16x8*)(Vb + (size_t)sr * T_ + sc);
    u16x8 pv1 = *(const u16x8*)(Vb + (size_t)(sr + 32) * T_ + sc);

    for (int kt = 0; kt < kend; kt += 64) {
        *(u16x8*)(sK + sr * 72 + sc) = pk0;
        *(u16x8*)(sK + (sr + 32) * 72 + sc) = pk1;
        *(u16x8*)(sVt + sr * 72 + sc) = pv0;
        *(u16x8*)(sVt + (sr + 32) * 72 + sc) = pv1;
        __syncthreads();

        const int ktn = kt + 64;
        if (ktn < kend) {  // prefetch next tile during compute
            pk0 = *(const u16x8*)(Kb + (size_t)(ktn + sr) * ND_ + sc);
            pk1 = *(const u16x8*)(Kb + (size_t)(ktn + sr + 32) * ND_ + sc);
            pv0 = *(const u16x8*)(Vb + (size_t)sr * T_ + ktn + sc);
            pv1 = *(const u16x8*)(Vb + (size_t)(sr + 32) * T_ + ktn + sc);
        }

        // QK^T per 16-k subtile, exp fused
#pragma unroll
        for (int ks = 0; ks < 4; ks++) {
            bf8 kb0 = *(const bf8*)(sK + (ks * 16 + l15) * 72 + qo);
            bf8 kb1 = *(const bf8*)(sK + (ks * 16 + l15) * 72 + 32 + qo);
            const int kg = kt + ks * 16 + l15;
            const float mk = mc[kg];
            const float il = ic[kg];
#pragma unroll
            for (int qs = 0; qs < 2; qs++) {
                f4 s = {0.f, 0.f, 0.f, 0.f};
                s = mfma16(aq[qs][0], kb0, s);
                s = mfma16(aq[qs][1], kb1, s);
#pragma unroll
                for (int r = 0; r < 4; r++) {
                    const int qg = qw + qs * 16 + quad * 4 + r;
                    const float p = (kg <= qg) ? __expf(s[r] * 0.125f - mk) * il : 0.f;
                    sP[wave][(qs * 16 + quad * 4 + r) * 72 + ks * 16 + l15] = f2bf(p);
                }
            }
        }
        // PV: A = sP (per-wave), B = sVt
#pragma unroll
        for (int st = 0; st < 2; st++) {
            bf8 ap0 = *(const bf8*)(&sP[wave][(l15) * 72 + st * 32 + qo]);
            bf8 ap1 = *(const bf8*)(&sP[wave][(16 + l15) * 72 + st * 32 + qo]);
#pragma unroll
            for (int ds = 0; ds < 4; ds++) {
                bf8 bv = *(const bf8*)(sVt + (ds * 16 + l15) * 72 + st * 32 + qo);
                o[0][ds] = mfma16(ap0, bv, o[0][ds]);
                o[1][ds] = mfma16(ap1, bv, o[1][ds]);
            }
        }
        __syncthreads();
    }

    // write AO[B,T,D] bf16
#pragma unroll
    for (int qs = 0; qs < 2; qs++)
#pragma unroll
        for (int ds = 0; ds < 4; ds++)
#pragma unroll
            for (int r = 0; r < 4; r++) {
                const int q = qw + qs * 16 + quad * 4 + r;
                const int d = ds * 16 + l15;
                AO[((size_t)(b * T_ + q)) * D_ + h * ND_ + d] = f2bf(o[qs][ds][r]);
            }
}

// ---------------------------------------------------------------------------
extern "C" void kernel_launch(void* const* d_in, const int* in_sizes, int n_in,
                              void* d_out, int out_size, void* d_ws, size_t ws_size,
                              hipStream_t stream) {
    (void)in_sizes; (void)n_in; (void)out_size; (void)ws_size;
    const float* q  = (const float*)d_in[0];
    // d_in[1]=k, d_in[2]=v dead (reference bug: K,V projected from q)
    const float* wq = (const float*)d_in[3];
    const float* bq = (const float*)d_in[4];
    const float* wk = (const float*)d_in[5];
    const float* bk = (const float*)d_in[6];
    const float* wv = (const float*)d_in[7];
    const float* bv = (const float*)d_in[8];
    const float* wo = (const float*)d_in[9];
    const float* bo = (const float*)d_in[10];
    // d_in[11] = mask: structurally tril, handled via k<=q

    const size_t SZ = (size_t)M_ * D_;
    const size_t WSZ = (size_t)D_ * D_;
    u16* Qh  = (u16*)d_ws;               // [B,H,T,64]
    u16* Kh  = Qh + SZ;
    u16* Vtr = Kh + SZ;                  // [B*H, 64, T] (transposed V)
    u16* qbf = Vtr + SZ;                 // q bf16; reused as AO
    u16* AO  = qbf;
    u16* wqb = qbf + SZ;
    u16* wkb = wqb + WSZ;
    u16* wvb = wkb + WSZ;
    u16* wob = wvb + WSZ;
    float* Mc = (float*)(wob + WSZ);
    float* Ic = Mc + (size_t)B_ * H_ * T_;

    cvt_bf16<<<dim3(SZ / 8 / 256), 256, 0, stream>>>(q, qbf, (int)SZ);
    cvt_bf16<<<dim3(WSZ / 8 / 256), 256, 0, stream>>>(wq, wqb, (int)WSZ);
    cvt_bf16<<<dim3(WSZ / 8 / 256), 256, 0, stream>>>(wk, wkb, (int)WSZ);
    cvt_bf16<<<dim3(WSZ / 8 / 256), 256, 0, stream>>>(wv, wvb, (int)WSZ);
    cvt_bf16<<<dim3(WSZ / 8 / 256), 256, 0, stream>>>(wo, wob, (int)WSZ);

    dim3 gp(D_ / 128, M_ / 128);         // (8, 64)
    gemm_bt<1><<<gp, 256, 0, stream>>>(qbf, wqb, bq, Qh);
    gemm_bt<1><<<gp, 256, 0, stream>>>(qbf, wkb, bk, Kh);
    gemm_bt<2><<<gp, 256, 0, stream>>>(qbf, wvb, bv, Vtr);

    dim3 gs(T_ / 64, B_ * H_);           // (32, 64)
    col_stats<<<gs, 256, 0, stream>>>(Qh, Kh, Mc, Ic);

    dim3 ga(B_ * H_, T_ / 128);          // (64, 16)
    attn_out<<<ga, 256, 0, stream>>>(Qh, Kh, Vtr, Mc, Ic, AO);

    gemm_bt<0><<<gp, 256, 0, stream>>>(AO, wob, bo, d_out);
}

// Round 5
// 466.051 us; speedup vs baseline: 1.7402x; 1.2961x over previous
//
#include <hip/hip_runtime.h>
#include <stdint.h>

// Problem constants
#define B_  4
#define T_  2048
#define D_  1024
#define H_  16
#define ND_ 64
#define M_  (B_ * T_)   // 8192 rows

typedef unsigned short u16;
typedef __bf16 bf8  __attribute__((ext_vector_type(8)));
typedef float  f4   __attribute__((ext_vector_type(4)));
typedef u16    u16x8 __attribute__((ext_vector_type(8)));

__device__ inline float bf2f(u16 b) {
    unsigned int x = ((unsigned int)b) << 16;
    return __builtin_bit_cast(float, x);
}
__device__ inline u16 f2bf(float f) {  // RNE, finite inputs only
    unsigned int x = __builtin_bit_cast(unsigned int, f);
    x += 0x7fffu + ((x >> 16) & 1u);
    return (u16)(x >> 16);
}
__device__ inline f4 mfma16(bf8 a, bf8 b, f4 c) {
    return __builtin_amdgcn_mfma_f32_16x16x32_bf16(a, b, c, 0, 0, 0);
}
// async global->LDS, 16B per lane; LDS dest = wave-uniform base + lane*16
__device__ inline void async16(const void* g, void* l) {
    auto gp = reinterpret_cast<const __attribute__((address_space(1))) unsigned int*>(
        reinterpret_cast<uintptr_t>(g));
    auto lp = reinterpret_cast<__attribute__((address_space(3))) unsigned int*>(
        reinterpret_cast<uintptr_t>(l));
    __builtin_amdgcn_global_load_lds(gp, lp, 16, 0, 0);
}

// ---------------------------------------------------------------------------
// fp32 -> bf16 elementwise convert (n divisible by 8)
// ---------------------------------------------------------------------------
__global__ __launch_bounds__(256)
void cvt_bf16(const float* __restrict__ in, u16* __restrict__ out, int n) {
    int i = (blockIdx.x * blockDim.x + threadIdx.x) * 8;
    if (i + 8 <= n) {
        float4 a = *(const float4*)(in + i);
        float4 b = *(const float4*)(in + i + 4);
        u16x8 o;
        o[0] = f2bf(a.x); o[1] = f2bf(a.y); o[2] = f2bf(a.z); o[3] = f2bf(a.w);
        o[4] = f2bf(b.x); o[5] = f2bf(b.y); o[6] = f2bf(b.z); o[7] = f2bf(b.w);
        *(u16x8*)(out + i) = o;
    }
}

// ---------------------------------------------------------------------------
// C[M,N] = A[M,K] @ W[N,K]^T + bias   (A,W bf16, fp32 accum, bias fp32)
// MODE 0: write C row-major [M,N] as FP32 (final output)
// MODE 1: write bf16 head layout: out[((b*H + h)*T + t)*64 + d]
// MODE 2: write bf16 transposed head layout: out[(bh*64 + d)*T + t]  (for V)
// Fixed: M=8192, N=1024, K=1024. Grid (8, 64), block 256.
// ---------------------------------------------------------------------------
template <int MODE>
__global__ __launch_bounds__(256, 2)
void gemm_bt(const u16* __restrict__ A, const u16* __restrict__ W,
             const float* __restrict__ bias, void* __restrict__ CoutV) {
    constexpr int K = 1024;
    constexpr int N = 1024;
    __shared__ __attribute__((aligned(16))) u16 sA[128 * 32];
    __shared__ __attribute__((aligned(16))) u16 sB[128 * 32];
    const int tid  = threadIdx.x;
    const int wave = tid >> 6;
    const int lane = tid & 63;
    const int m0 = blockIdx.y * 128;
    const int n0 = blockIdx.x * 128;
    const int wm = (wave & 1) * 64;
    const int wn = (wave >> 1) * 64;

    f4 acc[4][4] = {};

    const int srow = wave * 32 + (lane >> 2);
    const int scol = (lane & 3) * 8;
    const u16* gA = A + (size_t)(m0 + srow) * K + scol;
    const u16* gB = W + (size_t)(n0 + srow) * K + scol;
    u16* lA0 = sA + (wave * 32) * 32;
    u16* lA1 = sA + (wave * 32 + 16) * 32;
    u16* lB0 = sB + (wave * 32) * 32;
    u16* lB1 = sB + (wave * 32 + 16) * 32;

    const int row = lane & 15;
    const int qo  = (lane >> 4) * 8;

    for (int k0 = 0; k0 < K; k0 += 32) {
        async16(gA + k0, lA0);
        async16(gA + k0 + (size_t)16 * K, lA1);
        async16(gB + k0, lB0);
        async16(gB + k0 + (size_t)16 * K, lB1);
        __syncthreads();

        bf8 af[4], bfr[4];
#pragma unroll
        for (int i = 0; i < 4; i++)
            af[i] = *(const bf8*)(sA + (wm + i * 16 + row) * 32 + qo);
#pragma unroll
        for (int i = 0; i < 4; i++)
            bfr[i] = *(const bf8*)(sB + (wn + i * 16 + row) * 32 + qo);
#pragma unroll
        for (int mi = 0; mi < 4; mi++)
#pragma unroll
            for (int ni = 0; ni < 4; ni++)
                acc[mi][ni] = mfma16(af[mi], bfr[ni], acc[mi][ni]);
        __syncthreads();
    }

    // epilogue: C row m = m0+wm+mi*16+(lane>>4)*4+r, col n = n0+wn+ni*16+(lane&15)
#pragma unroll
    for (int ni = 0; ni < 4; ni++) {
        const int n = n0 + wn + ni * 16 + row;
        const float bv = bias[n];
#pragma unroll
        for (int mi = 0; mi < 4; mi++) {
#pragma unroll
            for (int r = 0; r < 4; r++) {
                const int m = m0 + wm + mi * 16 + (lane >> 4) * 4 + r;
                const float v = acc[mi][ni][r] + bv;
                if (MODE == 1) {
                    size_t idx = (((size_t)((m >> 11) * H_ + (n >> 6)) * T_) + (m & (T_ - 1))) * ND_ +
                                 (n & (ND_ - 1));
                    ((u16*)CoutV)[idx] = f2bf(v);
                } else if (MODE == 2) {
                    // Vt[(bh*64 + d)*T + t], bh=(m>>11)*16+(n>>6), d=n&63, t=m&2047
                    size_t idx = ((size_t)(((m >> 11) * H_ + (n >> 6)) * ND_ + (n & (ND_ - 1)))) * T_ +
                                 (m & (T_ - 1));
                    ((u16*)CoutV)[idx] = f2bf(v);
                } else {
                    ((float*)CoutV)[(size_t)m * N + n] = v;
                }
            }
        }
    }
}

// ---------------------------------------------------------------------------
// Column softmax denominators WITHOUT max subtraction (scores are O(6),
// exp fp32-safe to ~87): Ic[bh,k] = 1 / sum_{q>=k} exp(QK/8).
// Load-balanced: block x handles k-blocks {x, 31-x} -> exactly ~130 tiles
// per wave. Grid (16, B*H), block 256; wave owns 16 columns.
// All exps independent (4 accumulators), no serial softmax chain.
// ---------------------------------------------------------------------------
__global__ __launch_bounds__(256)
void col_sum(const u16* __restrict__ Qh, const u16* __restrict__ Kh,
             float* __restrict__ Ic) {
    const int bh   = blockIdx.y;
    const int wave = threadIdx.x >> 6;
    const int lane = threadIdx.x & 63;
    const int l15  = lane & 15;
    const int quad = lane >> 4;
    const int qo   = quad * 8;
    const u16* Qb = Qh + (size_t)bh * T_ * ND_;
    const u16* Kb = Kh + (size_t)bh * T_ * ND_;

#pragma unroll
    for (int half = 0; half < 2; half++) {
        const int kb   = half ? (31 - (int)blockIdx.x) : (int)blockIdx.x;
        const int k0   = kb * 64 + wave * 16;
        const int kcol = k0 + l15;
        const bf8 b0 = *(const bf8*)(Kb + (size_t)kcol * ND_ + qo);
        const bf8 b1 = *(const bf8*)(Kb + (size_t)kcol * ND_ + 32 + qo);

        f4 acc = {0.f, 0.f, 0.f, 0.f};
        {   // diagonal tile (element-masked)
            const u16* q0 = Qb + (size_t)(k0 + l15) * ND_;
            bf8 a0 = *(const bf8*)(q0 + qo);
            bf8 a1 = *(const bf8*)(q0 + 32 + qo);
            f4 s = {0.f, 0.f, 0.f, 0.f};
            s = mfma16(a0, b0, s);
            s = mfma16(a1, b1, s);
#pragma unroll
            for (int r = 0; r < 4; r++)
                acc[r] += (quad * 4 + r >= l15) ? __expf(s[r] * 0.125f) : 0.f;
        }
        int qt = k0 + 16;
        for (; qt + 32 <= T_; qt += 32) {  // 2 tiles/iter for exp ILP
            const u16* q0 = Qb + (size_t)(qt + l15) * ND_;
            const u16* q1 = Qb + (size_t)(qt + 16 + l15) * ND_;
            bf8 a00 = *(const bf8*)(q0 + qo);
            bf8 a01 = *(const bf8*)(q0 + 32 + qo);
            bf8 a10 = *(const bf8*)(q1 + qo);
            bf8 a11 = *(const bf8*)(q1 + 32 + qo);
            f4 s0 = {0.f, 0.f, 0.f, 0.f}, s1 = {0.f, 0.f, 0.f, 0.f};
            s0 = mfma16(a00, b0, s0);
            s0 = mfma16(a01, b1, s0);
            s1 = mfma16(a10, b0, s1);
            s1 = mfma16(a11, b1, s1);
#pragma unroll
            for (int r = 0; r < 4; r++) acc[r] += __expf(s0[r] * 0.125f);
#pragma unroll
            for (int r = 0; r < 4; r++) acc[r] += __expf(s1[r] * 0.125f);
        }
        if (qt < T_) {
            const u16* q0 = Qb + (size_t)(qt + l15) * ND_;
            bf8 a00 = *(const bf8*)(q0 + qo);
            bf8 a01 = *(const bf8*)(q0 + 32 + qo);
            f4 s0 = {0.f, 0.f, 0.f, 0.f};
            s0 = mfma16(a00, b0, s0);
            s0 = mfma16(a01, b1, s0);
#pragma unroll
            for (int r = 0; r < 4; r++) acc[r] += __expf(s0[r] * 0.125f);
        }
        float l = acc[0] + acc[1] + acc[2] + acc[3];
        l += __shfl_xor(l, 16);
        l += __shfl_xor(l, 32);
        if (lane < 16) Ic[(size_t)bh * T_ + kcol] = 1.f / l;
    }
}

// ---------------------------------------------------------------------------
// attn_out: 128 q rows/block, 64-key tiles, padded LDS stride 72, register
// prefetch, per-wave sP (no middle barrier). No max subtraction (matches
// col_sum). Vt pre-transposed per head: [bh][64 d][2048 t].
// Grid (B*H, T/128), heavy q-blocks dispatched first; block 256.
// ---------------------------------------------------------------------------
__global__ __launch_bounds__(256, 4)
void attn_out(const u16* __restrict__ Qh, const u16* __restrict__ Kh,
              const u16* __restrict__ Vt, const float* __restrict__ Ic,
              u16* __restrict__ AO) {
    __shared__ __attribute__((aligned(16))) u16 sK[64 * 72];    // [k][d] pad 72
    __shared__ __attribute__((aligned(16))) u16 sVt[64 * 72];   // [d][k] pad 72
    __shared__ __attribute__((aligned(16))) u16 sP[4][32 * 72]; // per-wave [q][k] pad 72
    const int bh   = blockIdx.x;
    const int b    = bh >> 4;
    const int h    = bh & 15;
    const int qb   = (int)(gridDim.y - 1 - blockIdx.y) * 128;  // heavy blocks first
    const int tid  = threadIdx.x;
    const int wave = tid >> 6;
    const int lane = tid & 63;
    const int l15  = lane & 15;
    const int quad = lane >> 4;
    const int qo   = quad * 8;

    const u16* Qb = Qh + (size_t)bh * T_ * ND_;
    const u16* Kb = Kh + (size_t)bh * T_ * ND_;
    const u16* Vb = Vt + (size_t)bh * ND_ * T_;   // [d][t]
    const float* ic = Ic + (size_t)bh * T_;

    // wave owns q rows [qw, qw+32)
    const int qw = qb + wave * 32;
    bf8 aq[2][2];
#pragma unroll
    for (int qs = 0; qs < 2; qs++)
#pragma unroll
        for (int dh = 0; dh < 2; dh++)
            aq[qs][dh] = *(const bf8*)(Qb + (size_t)(qw + qs * 16 + l15) * ND_ + dh * 32 + qo);

    f4 o[2][4] = {};

    const int sr = tid >> 3;        // 0..31
    const int sc = (tid & 7) * 8;   // 0..56
    const int kend = qb + 128;

    // prefetch tile kt=0
    u16x8 pk0 = *(const u16x8*)(Kb + (size_t)sr * ND_ + sc);
    u16x8 pk1 = *(const u16x8*)(Kb + (size_t)(sr + 32) * ND_ + sc);
    u16x8 pv0 = *(const u16x8*)(Vb + (size_t)sr * T_ + sc);
    u16x8 pv1 = *(const u16x8*)(Vb + (size_t)(sr + 32) * T_ + sc);

    for (int kt = 0; kt < kend; kt += 64) {
        *(u16x8*)(sK + sr * 72 + sc) = pk0;
        *(u16x8*)(sK + (sr + 32) * 72 + sc) = pk1;
        *(u16x8*)(sVt + sr * 72 + sc) = pv0;
        *(u16x8*)(sVt + (sr + 32) * 72 + sc) = pv1;
        __syncthreads();

        const int ktn = kt + 64;
        if (ktn < kend) {  // prefetch next tile during compute
            pk0 = *(const u16x8*)(Kb + (size_t)(ktn + sr) * ND_ + sc);
            pk1 = *(const u16x8*)(Kb + (size_t)(ktn + sr + 32) * ND_ + sc);
            pv0 = *(const u16x8*)(Vb + (size_t)sr * T_ + ktn + sc);
            pv1 = *(const u16x8*)(Vb + (size_t)(sr + 32) * T_ + ktn + sc);
        }

        // QK^T per 16-k subtile, exp fused
#pragma unroll
        for (int ks = 0; ks < 4; ks++) {
            bf8 kb0 = *(const bf8*)(sK + (ks * 16 + l15) * 72 + qo);
            bf8 kb1 = *(const bf8*)(sK + (ks * 16 + l15) * 72 + 32 + qo);
            const int kg = kt + ks * 16 + l15;
            const float il = ic[kg];
#pragma unroll
            for (int qs = 0; qs < 2; qs++) {
                f4 s = {0.f, 0.f, 0.f, 0.f};
                s = mfma16(aq[qs][0], kb0, s);
                s = mfma16(aq[qs][1], kb1, s);
#pragma unroll
                for (int r = 0; r < 4; r++) {
                    const int qg = qw + qs * 16 + quad * 4 + r;
                    const float p = (kg <= qg) ? __expf(s[r] * 0.125f) * il : 0.f;
                    sP[wave][(qs * 16 + quad * 4 + r) * 72 + ks * 16 + l15] = f2bf(p);
                }
            }
        }
        // PV: A = sP (per-wave), B = sVt
#pragma unroll
        for (int st = 0; st < 2; st++) {
            bf8 ap0 = *(const bf8*)(&sP[wave][(l15) * 72 + st * 32 + qo]);
            bf8 ap1 = *(const bf8*)(&sP[wave][(16 + l15) * 72 + st * 32 + qo]);
#pragma unroll
            for (int ds = 0; ds < 4; ds++) {
                bf8 bv = *(const bf8*)(sVt + (ds * 16 + l15) * 72 + st * 32 + qo);
                o[0][ds] = mfma16(ap0, bv, o[0][ds]);
                o[1][ds] = mfma16(ap1, bv, o[1][ds]);
            }
        }
        __syncthreads();
    }

    // write AO[B,T,D] bf16
#pragma unroll
    for (int qs = 0; qs < 2; qs++)
#pragma unroll
        for (int ds = 0; ds < 4; ds++)
#pragma unroll
            for (int r = 0; r < 4; r++) {
                const int q = qw + qs * 16 + quad * 4 + r;
                const int d = ds * 16 + l15;
                AO[((size_t)(b * T_ + q)) * D_ + h * ND_ + d] = f2bf(o[qs][ds][r]);
            }
}

// ---------------------------------------------------------------------------
extern "C" void kernel_launch(void* const* d_in, const int* in_sizes, int n_in,
                              void* d_out, int out_size, void* d_ws, size_t ws_size,
                              hipStream_t stream) {
    (void)in_sizes; (void)n_in; (void)out_size; (void)ws_size;
    const float* q  = (const float*)d_in[0];
    // d_in[1]=k, d_in[2]=v dead (reference bug: K,V projected from q)
    const float* wq = (const float*)d_in[3];
    const float* bq = (const float*)d_in[4];
    const float* wk = (const float*)d_in[5];
    const float* bk = (const float*)d_in[6];
    const float* wv = (const float*)d_in[7];
    const float* bv = (const float*)d_in[8];
    const float* wo = (const float*)d_in[9];
    const float* bo = (const float*)d_in[10];
    // d_in[11] = mask: structurally tril, handled via k<=q

    const size_t SZ = (size_t)M_ * D_;
    const size_t WSZ = (size_t)D_ * D_;
    u16* Qh  = (u16*)d_ws;               // [B,H,T,64]
    u16* Kh  = Qh + SZ;
    u16* Vtr = Kh + SZ;                  // [B*H, 64, T] (transposed V)
    u16* qbf = Vtr + SZ;                 // q bf16; reused as AO
    u16* AO  = qbf;
    u16* wqb = qbf + SZ;
    u16* wkb = wqb + WSZ;
    u16* wvb = wkb + WSZ;
    u16* wob = wvb + WSZ;
    float* Ic = (float*)(wob + WSZ);     // [B*H, T]

    cvt_bf16<<<dim3(SZ / 8 / 256), 256, 0, stream>>>(q, qbf, (int)SZ);
    cvt_bf16<<<dim3(WSZ / 8 / 256), 256, 0, stream>>>(wq, wqb, (int)WSZ);
    cvt_bf16<<<dim3(WSZ / 8 / 256), 256, 0, stream>>>(wk, wkb, (int)WSZ);
    cvt_bf16<<<dim3(WSZ / 8 / 256), 256, 0, stream>>>(wv, wvb, (int)WSZ);
    cvt_bf16<<<dim3(WSZ / 8 / 256), 256, 0, stream>>>(wo, wob, (int)WSZ);

    dim3 gp(D_ / 128, M_ / 128);         // (8, 64)
    gemm_bt<1><<<gp, 256, 0, stream>>>(qbf, wqb, bq, Qh);
    gemm_bt<1><<<gp, 256, 0, stream>>>(qbf, wkb, bk, Kh);
    gemm_bt<2><<<gp, 256, 0, stream>>>(qbf, wvb, bv, Vtr);

    dim3 gs(16, B_ * H_);                // load-balanced column sums
    col_sum<<<gs, 256, 0, stream>>>(Qh, Kh, Ic);

    dim3 ga(B_ * H_, T_ / 128);          // (64, 16)
    attn_out<<<ga, 256, 0, stream>>>(Qh, Kh, Vtr, Ic, AO);

    gemm_bt<0><<<gp, 256, 0, stream>>>(AO, wob, bo, d_out);
}

// Round 6
// 395.884 us; speedup vs baseline: 2.0486x; 1.1772x over previous
//
#include <hip/hip_runtime.h>
#include <stdint.h>

// Problem constants
#define B_  4
#define T_  2048
#define D_  1024
#define H_  16
#define ND_ 64
#define M_  (B_ * T_)   // 8192 rows

typedef unsigned short u16;
typedef __bf16 bf8  __attribute__((ext_vector_type(8)));
typedef float  f4   __attribute__((ext_vector_type(4)));
typedef u16    u16x8 __attribute__((ext_vector_type(8)));

__device__ inline float bf2f(u16 b) {
    unsigned int x = ((unsigned int)b) << 16;
    return __builtin_bit_cast(float, x);
}
__device__ inline u16 f2bf(float f) {  // RNE, finite inputs only
    unsigned int x = __builtin_bit_cast(unsigned int, f);
    x += 0x7fffu + ((x >> 16) & 1u);
    return (u16)(x >> 16);
}
__device__ inline f4 mfma16(bf8 a, bf8 b, f4 c) {
    return __builtin_amdgcn_mfma_f32_16x16x32_bf16(a, b, c, 0, 0, 0);
}
// async global->LDS, 16B per lane; LDS dest = wave-uniform base + lane*16
__device__ inline void async16(const void* g, void* l) {
    auto gp = reinterpret_cast<const __attribute__((address_space(1))) unsigned int*>(
        reinterpret_cast<uintptr_t>(g));
    auto lp = reinterpret_cast<__attribute__((address_space(3))) unsigned int*>(
        reinterpret_cast<uintptr_t>(l));
    __builtin_amdgcn_global_load_lds(gp, lp, 16, 0, 0);
}

// ---------------------------------------------------------------------------
// fp32 -> bf16 elementwise convert (n divisible by 8)
// ---------------------------------------------------------------------------
__global__ __launch_bounds__(256)
void cvt_bf16(const float* __restrict__ in, u16* __restrict__ out, int n) {
    int i = (blockIdx.x * blockDim.x + threadIdx.x) * 8;
    if (i + 8 <= n) {
        float4 a = *(const float4*)(in + i);
        float4 b = *(const float4*)(in + i + 4);
        u16x8 o;
        o[0] = f2bf(a.x); o[1] = f2bf(a.y); o[2] = f2bf(a.z); o[3] = f2bf(a.w);
        o[4] = f2bf(b.x); o[5] = f2bf(b.y); o[6] = f2bf(b.z); o[7] = f2bf(b.w);
        *(u16x8*)(out + i) = o;
    }
}

// ---------------------------------------------------------------------------
// C[M,N] = A[M,K] @ W[N,K]^T + bias   (A,W bf16, fp32 accum, bias fp32)
// MODE 0: write C row-major [M,N] as FP32 (final output)
// MODE 1: write bf16 head layout: out[((b*H + h)*T + t)*64 + d]
// MODE 2: write bf16 transposed head layout: out[(bh*64 + d)*T + t]  (for V)
// Fixed: M=8192, N=1024, K=1024. Grid (8, 64), block 256.
// ---------------------------------------------------------------------------
template <int MODE>
__global__ __launch_bounds__(256, 2)
void gemm_bt(const u16* __restrict__ A, const u16* __restrict__ W,
             const float* __restrict__ bias, void* __restrict__ CoutV) {
    constexpr int K = 1024;
    constexpr int N = 1024;
    __shared__ __attribute__((aligned(16))) u16 sA[128 * 32];
    __shared__ __attribute__((aligned(16))) u16 sB[128 * 32];
    const int tid  = threadIdx.x;
    const int wave = tid >> 6;
    const int lane = tid & 63;
    const int m0 = blockIdx.y * 128;
    const int n0 = blockIdx.x * 128;
    const int wm = (wave & 1) * 64;
    const int wn = (wave >> 1) * 64;

    f4 acc[4][4] = {};

    const int srow = wave * 32 + (lane >> 2);
    const int scol = (lane & 3) * 8;
    const u16* gA = A + (size_t)(m0 + srow) * K + scol;
    const u16* gB = W + (size_t)(n0 + srow) * K + scol;
    u16* lA0 = sA + (wave * 32) * 32;
    u16* lA1 = sA + (wave * 32 + 16) * 32;
    u16* lB0 = sB + (wave * 32) * 32;
    u16* lB1 = sB + (wave * 32 + 16) * 32;

    const int row = lane & 15;
    const int qo  = (lane >> 4) * 8;

    for (int k0 = 0; k0 < K; k0 += 32) {
        async16(gA + k0, lA0);
        async16(gA + k0 + (size_t)16 * K, lA1);
        async16(gB + k0, lB0);
        async16(gB + k0 + (size_t)16 * K, lB1);
        __syncthreads();

        bf8 af[4], bfr[4];
#pragma unroll
        for (int i = 0; i < 4; i++)
            af[i] = *(const bf8*)(sA + (wm + i * 16 + row) * 32 + qo);
#pragma unroll
        for (int i = 0; i < 4; i++)
            bfr[i] = *(const bf8*)(sB + (wn + i * 16 + row) * 32 + qo);
#pragma unroll
        for (int mi = 0; mi < 4; mi++)
#pragma unroll
            for (int ni = 0; ni < 4; ni++)
                acc[mi][ni] = mfma16(af[mi], bfr[ni], acc[mi][ni]);
        __syncthreads();
    }

    // epilogue: C row m = m0+wm+mi*16+(lane>>4)*4+r, col n = n0+wn+ni*16+(lane&15)
#pragma unroll
    for (int ni = 0; ni < 4; ni++) {
        const int n = n0 + wn + ni * 16 + row;
        const float bv = bias[n];
#pragma unroll
        for (int mi = 0; mi < 4; mi++) {
#pragma unroll
            for (int r = 0; r < 4; r++) {
                const int m = m0 + wm + mi * 16 + (lane >> 4) * 4 + r;
                const float v = acc[mi][ni][r] + bv;
                if (MODE == 1) {
                    size_t idx = (((size_t)((m >> 11) * H_ + (n >> 6)) * T_) + (m & (T_ - 1))) * ND_ +
                                 (n & (ND_ - 1));
                    ((u16*)CoutV)[idx] = f2bf(v);
                } else if (MODE == 2) {
                    // Vt[(bh*64 + d)*T + t], bh=(m>>11)*16+(n>>6), d=n&63, t=m&2047
                    size_t idx = ((size_t)(((m >> 11) * H_ + (n >> 6)) * ND_ + (n & (ND_ - 1)))) * T_ +
                                 (m & (T_ - 1));
                    ((u16*)CoutV)[idx] = f2bf(v);
                } else {
                    ((float*)CoutV)[(size_t)m * N + n] = v;
                }
            }
        }
    }
}

// ---------------------------------------------------------------------------
// Column softmax denominators WITHOUT max subtraction (scores are O(6),
// exp fp32-safe to ~87): Ic[bh,k] = 1 / sum_{q>=k} exp(QK/8).
// v3: Q staged through LDS (stride 72, conflict-free) shared by all 4
// waves; 128-col strip per block (32 cols/wave, B-frags in registers);
// double-buffered single-barrier stages with register prefetch.
// Strips paired {i, 15-i} -> every block exactly 68 stages.
// Grid (8, B*H), block 256.
// ---------------------------------------------------------------------------
__global__ __launch_bounds__(256)
void col_sum(const u16* __restrict__ Qh, const u16* __restrict__ Kh,
             float* __restrict__ Ic) {
    __shared__ __attribute__((aligned(16))) u16 sQ[2][32 * 72];
    const int bh   = blockIdx.y;
    const int tid  = threadIdx.x;
    const int wave = tid >> 6;
    const int lane = tid & 63;
    const int l15  = lane & 15;
    const int quad = lane >> 4;
    const int qo   = quad * 8;
    const int sr   = tid >> 3;       // 0..31
    const int sc   = (tid & 7) * 8;  // 0..56
    const u16* Qb = Qh + (size_t)bh * T_ * ND_;
    const u16* Kb = Kh + (size_t)bh * T_ * ND_;

#pragma unroll
    for (int half = 0; half < 2; half++) {
        const int strip = half ? (15 - (int)blockIdx.x) : (int)blockIdx.x;
        const int c0  = strip * 128;
        const int c0w = c0 + wave * 32;
        // B fragments: 32 columns per wave (2 groups of 16), d in 2 halves
        bf8 b0[2], b1[2];
#pragma unroll
        for (int g = 0; g < 2; g++) {
            b0[g] = *(const bf8*)(Kb + (size_t)(c0w + g * 16 + l15) * ND_ + qo);
            b1[g] = *(const bf8*)(Kb + (size_t)(c0w + g * 16 + l15) * ND_ + 32 + qo);
        }
        float acc[2][4] = {};
        int p = 0;
        u16x8 pq = *(const u16x8*)(Qb + (size_t)(c0 + sr) * ND_ + sc);
        for (int qt = c0; qt < T_; qt += 32) {
            *(u16x8*)(&sQ[p][sr * 72 + sc]) = pq;
            __syncthreads();
            if (qt + 32 < T_)
                pq = *(const u16x8*)(Qb + (size_t)(qt + 32 + sr) * ND_ + sc);
            const bool masked = qt < c0 + 128;  // wave-uniform
#pragma unroll
            for (int sub = 0; sub < 2; sub++) {
                const int rho = sub * 16 + l15;
                bf8 a0 = *(const bf8*)(&sQ[p][rho * 72 + qo]);
                bf8 a1 = *(const bf8*)(&sQ[p][rho * 72 + 32 + qo]);
#pragma unroll
                for (int g = 0; g < 2; g++) {
                    f4 s = {0.f, 0.f, 0.f, 0.f};
                    s = mfma16(a0, b0[g], s);
                    s = mfma16(a1, b1[g], s);
                    if (masked) {
#pragma unroll
                        for (int r = 0; r < 4; r++) {
                            const int qg = qt + sub * 16 + quad * 4 + r;
                            const int cg = c0w + g * 16 + l15;
                            acc[g][r] += (qg >= cg) ? __expf(s[r] * 0.125f) : 0.f;
                        }
                    } else {
#pragma unroll
                        for (int r = 0; r < 4; r++)
                            acc[g][r] += __expf(s[r] * 0.125f);
                    }
                }
            }
            p ^= 1;
        }
        __syncthreads();  // protect sQ reuse across strips
#pragma unroll
        for (int g = 0; g < 2; g++) {
            float l = acc[g][0] + acc[g][1] + acc[g][2] + acc[g][3];
            l += __shfl_xor(l, 16);
            l += __shfl_xor(l, 32);
            if (lane < 16) Ic[(size_t)bh * T_ + c0w + g * 16 + l15] = 1.f / l;
        }
    }
}

// ---------------------------------------------------------------------------
// attn_out: 128 q rows/block, 64-key tiles, padded LDS stride 72, register
// prefetch, per-wave sP (no middle barrier). No max subtraction (matches
// col_sum). Vt pre-transposed per head: [bh][64 d][2048 t].
// Grid (B*H, T/128), heavy q-blocks dispatched first; block 256.
// ---------------------------------------------------------------------------
__global__ __launch_bounds__(256, 4)
void attn_out(const u16* __restrict__ Qh, const u16* __restrict__ Kh,
              const u16* __restrict__ Vt, const float* __restrict__ Ic,
              u16* __restrict__ AO) {
    __shared__ __attribute__((aligned(16))) u16 sK[64 * 72];    // [k][d] pad 72
    __shared__ __attribute__((aligned(16))) u16 sVt[64 * 72];   // [d][k] pad 72
    __shared__ __attribute__((aligned(16))) u16 sP[4][32 * 72]; // per-wave [q][k] pad 72
    const int bh   = blockIdx.x;
    const int b    = bh >> 4;
    const int h    = bh & 15;
    const int qb   = (int)(gridDim.y - 1 - blockIdx.y) * 128;  // heavy blocks first
    const int tid  = threadIdx.x;
    const int wave = tid >> 6;
    const int lane = tid & 63;
    const int l15  = lane & 15;
    const int quad = lane >> 4;
    const int qo   = quad * 8;

    const u16* Qb = Qh + (size_t)bh * T_ * ND_;
    const u16* Kb = Kh + (size_t)bh * T_ * ND_;
    const u16* Vb = Vt + (size_t)bh * ND_ * T_;   // [d][t]
    const float* ic = Ic + (size_t)bh * T_;

    // wave owns q rows [qw, qw+32)
    const int qw = qb + wave * 32;
    bf8 aq[2][2];
#pragma unroll
    for (int qs = 0; qs < 2; qs++)
#pragma unroll
        for (int dh = 0; dh < 2; dh++)
            aq[qs][dh] = *(const bf8*)(Qb + (size_t)(qw + qs * 16 + l15) * ND_ + dh * 32 + qo);

    f4 o[2][4] = {};

    const int sr = tid >> 3;        // 0..31
    const int sc = (tid & 7) * 8;   // 0..56
    const int kend = qb + 128;

    // prefetch tile kt=0
    u16x8 pk0 = *(const u16x8*)(Kb + (size_t)sr * ND_ + sc);
    u16x8 pk1 = *(const u16x8*)(Kb + (size_t)(sr + 32) * ND_ + sc);
    u16x8 pv0 = *(const u16x8*)(Vb + (size_t)sr * T_ + sc);
    u16x8 pv1 = *(const u16x8*)(Vb + (size_t)(sr + 32) * T_ + sc);

    for (int kt = 0; kt < kend; kt += 64) {
        *(u16x8*)(sK + sr * 72 + sc) = pk0;
        *(u16x8*)(sK + (sr + 32) * 72 + sc) = pk1;
        *(u16x8*)(sVt + sr * 72 + sc) = pv0;
        *(u16x8*)(sVt + (sr + 32) * 72 + sc) = pv1;
        __syncthreads();

        const int ktn = kt + 64;
        if (ktn < kend) {  // prefetch next tile during compute
            pk0 = *(const u16x8*)(Kb + (size_t)(ktn + sr) * ND_ + sc);
            pk1 = *(const u16x8*)(Kb + (size_t)(ktn + sr + 32) * ND_ + sc);
            pv0 = *(const u16x8*)(Vb + (size_t)sr * T_ + ktn + sc);
            pv1 = *(const u16x8*)(Vb + (size_t)(sr + 32) * T_ + ktn + sc);
        }

        // QK^T per 16-k subtile, exp fused
#pragma unroll
        for (int ks = 0; ks < 4; ks++) {
            bf8 kb0 = *(const bf8*)(sK + (ks * 16 + l15) * 72 + qo);
            bf8 kb1 = *(const bf8*)(sK + (ks * 16 + l15) * 72 + 32 + qo);
            const int kg = kt + ks * 16 + l15;
            const float il = ic[kg];
#pragma unroll
            for (int qs = 0; qs < 2; qs++) {
                f4 s = {0.f, 0.f, 0.f, 0.f};
                s = mfma16(aq[qs][0], kb0, s);
                s = mfma16(aq[qs][1], kb1, s);
#pragma unroll
                for (int r = 0; r < 4; r++) {
                    const int qg = qw + qs * 16 + quad * 4 + r;
                    const float p = (kg <= qg) ? __expf(s[r] * 0.125f) * il : 0.f;
                    sP[wave][(qs * 16 + quad * 4 + r) * 72 + ks * 16 + l15] = f2bf(p);
                }
            }
        }
        // PV: A = sP (per-wave), B = sVt
#pragma unroll
        for (int st = 0; st < 2; st++) {
            bf8 ap0 = *(const bf8*)(&sP[wave][(l15) * 72 + st * 32 + qo]);
            bf8 ap1 = *(const bf8*)(&sP[wave][(16 + l15) * 72 + st * 32 + qo]);
#pragma unroll
            for (int ds = 0; ds < 4; ds++) {
                bf8 bv = *(const bf8*)(sVt + (ds * 16 + l15) * 72 + st * 32 + qo);
                o[0][ds] = mfma16(ap0, bv, o[0][ds]);
                o[1][ds] = mfma16(ap1, bv, o[1][ds]);
            }
        }
        __syncthreads();
    }

    // write AO[B,T,D] bf16
#pragma unroll
    for (int qs = 0; qs < 2; qs++)
#pragma unroll
        for (int ds = 0; ds < 4; ds++)
#pragma unroll
            for (int r = 0; r < 4; r++) {
                const int q = qw + qs * 16 + quad * 4 + r;
                const int d = ds * 16 + l15;
                AO[((size_t)(b * T_ + q)) * D_ + h * ND_ + d] = f2bf(o[qs][ds][r]);
            }
}

// ---------------------------------------------------------------------------
extern "C" void kernel_launch(void* const* d_in, const int* in_sizes, int n_in,
                              void* d_out, int out_size, void* d_ws, size_t ws_size,
                              hipStream_t stream) {
    (void)in_sizes; (void)n_in; (void)out_size; (void)ws_size;
    const float* q  = (const float*)d_in[0];
    // d_in[1]=k, d_in[2]=v dead (reference bug: K,V projected from q)
    const float* wq = (const float*)d_in[3];
    const float* bq = (const float*)d_in[4];
    const float* wk = (const float*)d_in[5];
    const float* bk = (const float*)d_in[6];
    const float* wv = (const float*)d_in[7];
    const float* bv = (const float*)d_in[8];
    const float* wo = (const float*)d_in[9];
    const float* bo = (const float*)d_in[10];
    // d_in[11] = mask: structurally tril, handled via k<=q

    const size_t SZ = (size_t)M_ * D_;
    const size_t WSZ = (size_t)D_ * D_;
    u16* Qh  = (u16*)d_ws;               // [B,H,T,64]
    u16* Kh  = Qh + SZ;
    u16* Vtr = Kh + SZ;                  // [B*H, 64, T] (transposed V)
    u16* qbf = Vtr + SZ;                 // q bf16; reused as AO
    u16* AO  = qbf;
    u16* wqb = qbf + SZ;
    u16* wkb = wqb + WSZ;
    u16* wvb = wkb + WSZ;
    u16* wob = wvb + WSZ;
    float* Ic = (float*)(wob + WSZ);     // [B*H, T]

    cvt_bf16<<<dim3(SZ / 8 / 256), 256, 0, stream>>>(q, qbf, (int)SZ);
    cvt_bf16<<<dim3(WSZ / 8 / 256), 256, 0, stream>>>(wq, wqb, (int)WSZ);
    cvt_bf16<<<dim3(WSZ / 8 / 256), 256, 0, stream>>>(wk, wkb, (int)WSZ);
    cvt_bf16<<<dim3(WSZ / 8 / 256), 256, 0, stream>>>(wv, wvb, (int)WSZ);
    cvt_bf16<<<dim3(WSZ / 8 / 256), 256, 0, stream>>>(wo, wob, (int)WSZ);

    dim3 gp(D_ / 128, M_ / 128);         // (8, 64)
    gemm_bt<1><<<gp, 256, 0, stream>>>(qbf, wqb, bq, Qh);
    gemm_bt<1><<<gp, 256, 0, stream>>>(qbf, wkb, bk, Kh);
    gemm_bt<2><<<gp, 256, 0, stream>>>(qbf, wvb, bv, Vtr);

    dim3 gcs(8, B_ * H_);                // LDS-staged, load-balanced column sums
    col_sum<<<gcs, 256, 0, stream>>>(Qh, Kh, Ic);

    dim3 ga(B_ * H_, T_ / 128);          // (64, 16)
    attn_out<<<ga, 256, 0, stream>>>(Qh, Kh, Vtr, Ic, AO);

    gemm_bt<0><<<gp, 256, 0, stream>>>(AO, wob, bo, d_out);
}